// Round 2
// baseline (2199.752 us; speedup 1.0000x reference)
//
#include <hip/hip_runtime.h>

#define NPTS   16384
#define NCLOUD 2
#define NTOT   (NPTS*NCLOUD)
#define CDIM   256
#define IDIM   128
#define KNN    16

// ---------------- build AB = [W1_top + W1_bot | W1_bot]  (256 x 256) ------
__global__ __launch_bounds__(256) void build_ab_kernel(
        const float* __restrict__ W1, float* __restrict__ AB) {
    int i = blockIdx.x * 256 + threadIdx.x;        // 0 .. 65535
    int c = i >> 8, col = i & 255;
    float v;
    if (col < IDIM) v = W1[c*IDIM + col] + W1[(c+CDIM)*IDIM + col];
    else            v = W1[(c+CDIM)*IDIM + (col-IDIM)];
    AB[i] = v;
}

// ---------------- brute-force kNN (per-thread sorted top-16) --------------
__global__ __launch_bounds__(128) void knn_kernel(
        const float* __restrict__ coords,
        float* __restrict__ knn_d2, int* __restrict__ knn_idx) {
    __shared__ float4 tile[1024];
    const int tid = threadIdx.x;
    const int ng  = blockIdx.x * 128 + tid;     // global query row
    const int b   = blockIdx.x >> 7;            // cloud id (128 blocks/cloud)
    const float* cb = coords + (size_t)b * NPTS * 3;

    const float qx = coords[(size_t)ng*3+0];
    const float qy = coords[(size_t)ng*3+1];
    const float qz = coords[(size_t)ng*3+2];

    float d[KNN];
    int   id[KNN];
#pragma unroll
    for (int s = 0; s < KNN; ++s) { d[s] = 3.4e38f; id[s] = 0; }

    for (int t = 0; t < NPTS/1024; ++t) {
        const int base = t * 1024;
        __syncthreads();
#pragma unroll
        for (int u = 0; u < 8; ++u) {
            int i = tid + u*128;
            int j = base + i;
            tile[i] = make_float4(cb[(size_t)j*3+0], cb[(size_t)j*3+1],
                                  cb[(size_t)j*3+2], 0.0f);
        }
        __syncthreads();
#pragma unroll 4
        for (int j = 0; j < 1024; ++j) {
            float4 cc = tile[j];
            float dx = qx - cc.x, dy = qy - cc.y, dz = qz - cc.z;
            float d2 = dx*dx + dy*dy + dz*dz;
            if (d2 < d[KNN-1]) {                 // rare: ~111 inserts / 16384
                int jj = b*NPTS + base + j;      // store GLOBAL row index
                bool sh_above = true;
#pragma unroll
                for (int s = KNN-1; s > 0; --s) {
                    bool sh = d2 < d[s-1];
                    float nd = sh ? d[s-1] : (sh_above ? d2 : d[s]);
                    int   ni = sh ? id[s-1] : (sh_above ? jj : id[s]);
                    d[s] = nd; id[s] = ni;
                    sh_above = sh;
                }
                if (sh_above) { d[0] = d2; id[0] = jj; }
            }
        }
    }
#pragma unroll
    for (int s = 0; s < KNN; ++s) {
        knn_d2 [(size_t)ng*KNN + s] = d[s];
        knn_idx[(size_t)ng*KNN + s] = id[s];
    }
}

// ---------------- fp32 GEMM: C[M,N] = A[M,K] @ B[K,N] (+bias) -------------
// tile 128x64, 256 threads, 8x4 per thread, BK=16
template<int KDIM>
__global__ __launch_bounds__(256) void gemm_kernel(
        const float* __restrict__ A, const float* __restrict__ B,
        const float* __restrict__ bias, float* __restrict__ C_,
        int M, int N) {
    __shared__ float As[16][132];   // [k][m], stride 132*4B (16B aligned)
    __shared__ float Bs[16][68];    // [k][n]
    const int tid = threadIdx.x;
    const int tx = tid & 15, ty = tid >> 4;
    const int bm = blockIdx.x * 128, bn = blockIdx.y * 64;
    float acc[8][4] = {};

    for (int k0 = 0; k0 < KDIM; k0 += 16) {
#pragma unroll
        for (int u = 0; u < 8; ++u) {
            int kk = tid & 15, mm = (tid >> 4) + u*16;
            As[kk][mm] = A[(size_t)(bm+mm)*KDIM + k0 + kk];
        }
#pragma unroll
        for (int u = 0; u < 4; ++u) {
            int col = tid & 63, row = (tid >> 6) + u*4;
            Bs[row][col] = B[(size_t)(row + k0)*N + bn + col];
        }
        __syncthreads();
#pragma unroll
        for (int kk = 0; kk < 16; ++kk) {
            float4 a0 = *(const float4*)&As[kk][ty*8];
            float4 a1 = *(const float4*)&As[kk][ty*8+4];
            float4 bv = *(const float4*)&Bs[kk][tx*4];
            float av[8] = {a0.x,a0.y,a0.z,a0.w,a1.x,a1.y,a1.z,a1.w};
            float bw[4] = {bv.x,bv.y,bv.z,bv.w};
#pragma unroll
            for (int i = 0; i < 8; ++i)
#pragma unroll
                for (int j = 0; j < 4; ++j)
                    acc[i][j] += av[i] * bw[j];
        }
        __syncthreads();
    }
#pragma unroll
    for (int i = 0; i < 8; ++i) {
        int m = bm + ty*8 + i;
#pragma unroll
        for (int j = 0; j < 4; ++j) {
            int n = bn + tx*4 + j;
            float v = acc[i][j];
            if (bias) v += bias[n];
            C_[(size_t)m*N + n] = v;
        }
    }
}

// ---------------- softmax weights + weighted relu gather ------------------
// hbar[n][t] = sum_k w_k * relu(P[idx_k][t] - Q[n][t] + b1[t])
__global__ __launch_bounds__(128) void combine_kernel(
        const float* __restrict__ PQ, const float* __restrict__ knn_d2,
        const int* __restrict__ knn_idx, const float* __restrict__ b1,
        float* __restrict__ hbar) {
    const int n = blockIdx.x;
    const int t = threadIdx.x;
    float dd[KNN];
#pragma unroll
    for (int k = 0; k < KNN; ++k) dd[k] = knn_d2[(size_t)n*KNN + k];
    float m = dd[0];
#pragma unroll
    for (int k = 1; k < KNN; ++k) m = fminf(m, dd[k]);
    float e[KNN]; float sum = 0.f;
#pragma unroll
    for (int k = 0; k < KNN; ++k) { e[k] = __expf(m - dd[k]); sum += e[k]; }
    const float inv = 1.0f / sum;
    const float q  = PQ[(size_t)n*CDIM + IDIM + t];
    const float bb = b1[t];
    float acc = 0.f;
#pragma unroll
    for (int k = 0; k < KNN; ++k) {
        int row = knn_idx[(size_t)n*KNN + k];
        float p = PQ[(size_t)row*CDIM + t];
        acc += e[k] * fmaxf(p - q + bb, 0.0f);
    }
    hbar[(size_t)n*IDIM + t] = acc * inv;
}

// --------------------------------------------------------------------------
extern "C" void kernel_launch(void* const* d_in, const int* in_sizes, int n_in,
                              void* d_out, int out_size, void* d_ws, size_t ws_size,
                              hipStream_t stream) {
    const float* coords = (const float*)d_in[0];   // (2,16384,3)
    const float* feats  = (const float*)d_in[1];   // (2,16384,256)
    const float* W1     = (const float*)d_in[2];   // (512,128)
    const float* b1     = (const float*)d_in[3];   // (128,)
    const float* W2     = (const float*)d_in[4];   // (128,256)
    const float* b2     = (const float*)d_in[5];   // (256,)
    float* out = (float*)d_out;                    // (2,16384,256)

    float* ws = (float*)d_ws;
    float* AB      = ws;                                 // 65536 f
    float* PQ      = AB + 65536;                         // 32768*256 f
    float* knn_d2  = PQ + (size_t)NTOT*CDIM;             // 32768*16 f
    int*   knn_idx = (int*)(knn_d2 + (size_t)NTOT*KNN);  // 32768*16 i
    float* hbar    = (float*)(knn_idx + (size_t)NTOT*KNN); // 32768*128 f
    // total ~55 MB of d_ws

    build_ab_kernel<<<256, 256, 0, stream>>>(W1, AB);
    knn_kernel<<<NTOT/128, 128, 0, stream>>>(coords, knn_d2, knn_idx);
    gemm_kernel<CDIM><<<dim3(NTOT/128, 256/64), 256, 0, stream>>>(
        feats, AB, nullptr, PQ, NTOT, 256);
    combine_kernel<<<NTOT, 128, 0, stream>>>(PQ, knn_d2, knn_idx, b1, hbar);
    gemm_kernel<IDIM><<<dim3(NTOT/128, 256/64), 256, 0, stream>>>(
        hbar, W2, b2, out, NTOT, 256);
}

// Round 3
// 404.380 us; speedup vs baseline: 5.4398x; 5.4398x over previous
//
#include <hip/hip_runtime.h>

#define NPTS   16384
#define NCLOUD 2
#define NTOT   (NPTS*NCLOUD)
#define CDIM   256
#define IDIM   128
#define KNN    16
#define GS     16                 // grid cells per axis
#define NCELL  (GS*GS*GS)         // 4096 per cloud
#define CELL_H 6.25f
#define INV_H  0.16f              // GS / 100.0

__device__ __forceinline__ int cell_coord(float v) {
    int c = (int)(v * INV_H);
    return c < 0 ? 0 : (c > GS-1 ? GS-1 : c);
}

// ---------------- build AB = [W1_top + W1_bot | W1_bot]  (256 x 256) ------
__global__ __launch_bounds__(256) void build_ab_kernel(
        const float* __restrict__ W1, float* __restrict__ AB) {
    int i = blockIdx.x * 256 + threadIdx.x;        // 0 .. 65535
    int c = i >> 8, col = i & 255;
    float v;
    if (col < IDIM) v = W1[c*IDIM + col] + W1[(c+CDIM)*IDIM + col];
    else            v = W1[(c+CDIM)*IDIM + (col-IDIM)];
    AB[i] = v;
}

// ---------------- grid build: count / scan / scatter ----------------------
__global__ __launch_bounds__(256) void count_kernel(
        const float* __restrict__ coords, int* __restrict__ cnt) {
    int t = blockIdx.x * 256 + threadIdx.x;        // 0..NTOT-1
    float x = coords[(size_t)t*3+0], y = coords[(size_t)t*3+1], z = coords[(size_t)t*3+2];
    int g = (t >> 14) * NCELL +
            (cell_coord(z)*GS + cell_coord(y))*GS + cell_coord(x);
    atomicAdd(&cnt[g], 1);
}

__global__ __launch_bounds__(1024) void scan_kernel(
        const int* __restrict__ cnt, int* __restrict__ cellstart,
        int* __restrict__ cursor) {
    __shared__ int sums[1024];
    const int tid = threadIdx.x;
    int local[8];
    int s = 0;
#pragma unroll
    for (int j = 0; j < 8; ++j) { local[j] = cnt[tid*8+j]; s += local[j]; }
    sums[tid] = s;
    __syncthreads();
    for (int off = 1; off < 1024; off <<= 1) {   // Hillis-Steele inclusive
        int v = (tid >= off) ? sums[tid-off] : 0;
        __syncthreads();
        sums[tid] += v;
        __syncthreads();
    }
    int run = sums[tid] - s;                     // exclusive base
#pragma unroll
    for (int j = 0; j < 8; ++j) {
        cellstart[tid*8+j] = run; cursor[tid*8+j] = run; run += local[j];
    }
    if (tid == 1023) cellstart[2*NCELL] = run;   // == NTOT
}

__global__ __launch_bounds__(256) void scatter_kernel(
        const float* __restrict__ coords, int* __restrict__ cursor,
        float4* __restrict__ sorted) {
    int t = blockIdx.x * 256 + threadIdx.x;
    float x = coords[(size_t)t*3+0], y = coords[(size_t)t*3+1], z = coords[(size_t)t*3+2];
    int g = (t >> 14) * NCELL +
            (cell_coord(z)*GS + cell_coord(y))*GS + cell_coord(x);
    int pos = atomicAdd(&cursor[g], 1);
    sorted[pos] = make_float4(x, y, z, __int_as_float(t));
}

// ---------------- grid kNN: expanding Chebyshev rings, exact --------------
__global__ __launch_bounds__(128) void knn_grid_kernel(
        const float4* __restrict__ sorted, const int* __restrict__ cellstart,
        float* __restrict__ knn_d2, int* __restrict__ knn_idx) {
    const int t = blockIdx.x * 128 + threadIdx.x;   // sorted-order query
    const float4 q = sorted[t];
    const int cbase = (t >> 14) * NCELL;            // cloud base cell
    const float qx = q.x, qy = q.y, qz = q.z;
    const int qi = __float_as_int(q.w);             // original global row
    const int cx = cell_coord(qx), cy = cell_coord(qy), cz = cell_coord(qz);

    float d[KNN];
    int   id[KNN];
#pragma unroll
    for (int s = 0; s < KNN; ++s) { d[s] = 3.4e38f; id[s] = 0; }

    for (int R = 0; R <= GS-1; ++R) {
        const int zlo = cz-R < 0 ? 0 : cz-R, zhi = cz+R > GS-1 ? GS-1 : cz+R;
        const int ylo = cy-R < 0 ? 0 : cy-R, yhi = cy+R > GS-1 ? GS-1 : cy+R;
        const int xlo = cx-R < 0 ? 0 : cx-R, xhi = cx+R > GS-1 ? GS-1 : cx+R;
        for (int icz = zlo; icz <= zhi; ++icz)
        for (int icy = ylo; icy <= yhi; ++icy)
        for (int icx = xlo; icx <= xhi; ++icx) {
            // shell only: skip interior (already scanned at smaller R)
            if (icx-cx != R && cx-icx != R && icy-cy != R && cy-icy != R &&
                icz-cz != R && cz-icz != R) continue;
            const int g = cbase + (icz*GS + icy)*GS + icx;
            const int p1 = cellstart[g+1];
            for (int p = cellstart[g]; p < p1; ++p) {
                float4 c = sorted[p];
                float dx = qx-c.x, dy = qy-c.y, dz = qz-c.z;
                float d2 = dx*dx + dy*dy + dz*dz;
                if (d2 < d[KNN-1]) {
                    int jj = __float_as_int(c.w);
                    bool sh_above = true;
#pragma unroll
                    for (int s = KNN-1; s > 0; --s) {
                        bool sh = d2 < d[s-1];
                        float nd = sh ? d[s-1] : (sh_above ? d2 : d[s]);
                        int   ni = sh ? id[s-1] : (sh_above ? jj : id[s]);
                        d[s] = nd; id[s] = ni;
                        sh_above = sh;
                    }
                    if (sh_above) { d[0] = d2; id[0] = jj; }
                }
            }
        }
        // exact-termination bound: distance to nearest unscanned cell face
        float gxl = (cx-R >= 1)    ? qx - (float)(cx-R)*CELL_H   : 1e30f;
        float gxh = (cx+R <= GS-2) ? (float)(cx+R+1)*CELL_H - qx : 1e30f;
        float gyl = (cy-R >= 1)    ? qy - (float)(cy-R)*CELL_H   : 1e30f;
        float gyh = (cy+R <= GS-2) ? (float)(cy+R+1)*CELL_H - qy : 1e30f;
        float gzl = (cz-R >= 1)    ? qz - (float)(cz-R)*CELL_H   : 1e30f;
        float gzh = (cz+R <= GS-2) ? (float)(cz+R+1)*CELL_H - qz : 1e30f;
        float bnd = fminf(fminf(fminf(gxl,gxh), fminf(gyl,gyh)), fminf(gzl,gzh));
        if (d[KNN-1] <= bnd*bnd) break;
    }
#pragma unroll
    for (int s = 0; s < KNN; ++s) {
        knn_d2 [(size_t)qi*KNN + s] = d[s];
        knn_idx[(size_t)qi*KNN + s] = id[s];
    }
}

// ---------------- fp32 GEMM: C[M,N] = A[M,K] @ B[K,N] (+bias) -------------
template<int KDIM>
__global__ __launch_bounds__(256) void gemm_kernel(
        const float* __restrict__ A, const float* __restrict__ B,
        const float* __restrict__ bias, float* __restrict__ C_,
        int M, int N) {
    __shared__ float As[16][132];
    __shared__ float Bs[16][68];
    const int tid = threadIdx.x;
    const int tx = tid & 15, ty = tid >> 4;
    const int bm = blockIdx.x * 128, bn = blockIdx.y * 64;
    float acc[8][4] = {};

    for (int k0 = 0; k0 < KDIM; k0 += 16) {
#pragma unroll
        for (int u = 0; u < 8; ++u) {
            int kk = tid & 15, mm = (tid >> 4) + u*16;
            As[kk][mm] = A[(size_t)(bm+mm)*KDIM + k0 + kk];
        }
#pragma unroll
        for (int u = 0; u < 4; ++u) {
            int col = tid & 63, row = (tid >> 6) + u*4;
            Bs[row][col] = B[(size_t)(row + k0)*N + bn + col];
        }
        __syncthreads();
#pragma unroll
        for (int kk = 0; kk < 16; ++kk) {
            float4 a0 = *(const float4*)&As[kk][ty*8];
            float4 a1 = *(const float4*)&As[kk][ty*8+4];
            float4 bv = *(const float4*)&Bs[kk][tx*4];
            float av[8] = {a0.x,a0.y,a0.z,a0.w,a1.x,a1.y,a1.z,a1.w};
            float bw[4] = {bv.x,bv.y,bv.z,bv.w};
#pragma unroll
            for (int i = 0; i < 8; ++i)
#pragma unroll
                for (int j = 0; j < 4; ++j)
                    acc[i][j] += av[i] * bw[j];
        }
        __syncthreads();
    }
#pragma unroll
    for (int i = 0; i < 8; ++i) {
        int m = bm + ty*8 + i;
#pragma unroll
        for (int j = 0; j < 4; ++j) {
            int n = bn + tx*4 + j;
            float v = acc[i][j];
            if (bias) v += bias[n];
            C_[(size_t)m*N + n] = v;
        }
    }
}

// ---------------- softmax weights + weighted relu gather ------------------
__global__ __launch_bounds__(128) void combine_kernel(
        const float* __restrict__ PQ, const float* __restrict__ knn_d2,
        const int* __restrict__ knn_idx, const float* __restrict__ b1,
        float* __restrict__ hbar) {
    const int n = blockIdx.x;
    const int t = threadIdx.x;
    float dd[KNN];
#pragma unroll
    for (int k = 0; k < KNN; ++k) dd[k] = knn_d2[(size_t)n*KNN + k];
    float m = dd[0];
#pragma unroll
    for (int k = 1; k < KNN; ++k) m = fminf(m, dd[k]);
    float e[KNN]; float sum = 0.f;
#pragma unroll
    for (int k = 0; k < KNN; ++k) { e[k] = __expf(m - dd[k]); sum += e[k]; }
    const float inv = 1.0f / sum;
    const float qv = PQ[(size_t)n*CDIM + IDIM + t];
    const float bb = b1[t];
    float acc = 0.f;
#pragma unroll
    for (int k = 0; k < KNN; ++k) {
        int row = knn_idx[(size_t)n*KNN + k];
        float p = PQ[(size_t)row*CDIM + t];
        acc += e[k] * fmaxf(p - qv + bb, 0.0f);
    }
    hbar[(size_t)n*IDIM + t] = acc * inv;
}

// --------------------------------------------------------------------------
extern "C" void kernel_launch(void* const* d_in, const int* in_sizes, int n_in,
                              void* d_out, int out_size, void* d_ws, size_t ws_size,
                              hipStream_t stream) {
    const float* coords = (const float*)d_in[0];   // (2,16384,3)
    const float* feats  = (const float*)d_in[1];   // (2,16384,256)
    const float* W1     = (const float*)d_in[2];   // (512,128)
    const float* b1     = (const float*)d_in[3];   // (128,)
    const float* W2     = (const float*)d_in[4];   // (128,256)
    const float* b2     = (const float*)d_in[5];   // (256,)
    float* out = (float*)d_out;                    // (2,16384,256)

    float* ws = (float*)d_ws;
    float* AB      = ws;                                   // 65536 f
    float* PQ      = AB + 65536;                           // 8 M f
    float* knn_d2  = PQ + (size_t)NTOT*CDIM;               // 512 K f
    int*   knn_idx = (int*)(knn_d2 + (size_t)NTOT*KNN);    // 512 K i
    float* hbar    = (float*)(knn_idx + (size_t)NTOT*KNN); // 4 M f
    int*   cnt       = (int*)(hbar + (size_t)NTOT*IDIM);   // 8192 i
    int*   cellstart = cnt + 2*NCELL;                      // 8193 i
    int*   cursor    = cellstart + 2*NCELL + 1;            // 8192 i
    float4* sorted   = (float4*)(cursor + 2*NCELL);        // 32768 float4
    // total ~56 MB of d_ws

    hipMemsetAsync(cnt, 0, 2*NCELL*sizeof(int), stream);
    build_ab_kernel<<<256, 256, 0, stream>>>(W1, AB);
    count_kernel  <<<NTOT/256, 256, 0, stream>>>(coords, cnt);
    scan_kernel   <<<1, 1024, 0, stream>>>(cnt, cellstart, cursor);
    scatter_kernel<<<NTOT/256, 256, 0, stream>>>(coords, cursor, sorted);
    knn_grid_kernel<<<NTOT/128, 128, 0, stream>>>(sorted, cellstart, knn_d2, knn_idx);
    gemm_kernel<CDIM><<<dim3(NTOT/128, 256/64), 256, 0, stream>>>(
        feats, AB, nullptr, PQ, NTOT, 256);
    combine_kernel<<<NTOT, 128, 0, stream>>>(PQ, knn_d2, knn_idx, b1, hbar);
    gemm_kernel<IDIM><<<dim3(NTOT/128, 256/64), 256, 0, stream>>>(
        hbar, W2, b2, out, NTOT, 256);
}

// Round 7
// 363.911 us; speedup vs baseline: 6.0448x; 1.1112x over previous
//
#include <hip/hip_runtime.h>
#include <hip/hip_bf16.h>

#define NPTS   16384
#define NCLOUD 2
#define NTOT   (NPTS*NCLOUD)
#define CDIM   256
#define IDIM   128
#define KNN    16
#define GS     16
#define NCELL  (GS*GS*GS)
#define CELL_H 6.25f
#define INV_H  0.16f

typedef __attribute__((ext_vector_type(8))) short s16x8;
typedef __attribute__((ext_vector_type(4))) float f32x4;

__device__ __forceinline__ int cell_coord(float v) {
    int c = (int)(v * INV_H);
    return c < 0 ? 0 : (c > GS-1 ? GS-1 : c);
}

// ---------------- prep: ABT = [W1_top+W1_bot | W1_bot]^T, W2T --------------
__global__ __launch_bounds__(256) void prep_kernel(
        const float* __restrict__ W1, const float* __restrict__ W2,
        float* __restrict__ ABTf, float* __restrict__ W2Tf) {
    int i = blockIdx.x*256 + threadIdx.x;
    if (i < 65536) {
        int n = i >> 8, k = i & 255;          // ABT[n][k] = AB[k][n]
        float v = (n < IDIM) ? (W1[k*IDIM + n] + W1[(k+CDIM)*IDIM + n])
                             : W1[(k+CDIM)*IDIM + (n-IDIM)];
        ABTf[n*CDIM + k] = v;
    } else {
        int j = i - 65536;                    // W2T[n][k] = W2[k][n]
        int n = j >> 7, k = j & 127;
        W2Tf[n*IDIM + k] = W2[k*CDIM + n];
    }
}

// ---------------- grid build ----------------------------------------------
__global__ __launch_bounds__(256) void count_kernel(
        const float* __restrict__ coords, int* __restrict__ cnt) {
    int t = blockIdx.x * 256 + threadIdx.x;
    float x = coords[(size_t)t*3+0], y = coords[(size_t)t*3+1], z = coords[(size_t)t*3+2];
    int g = (t >> 14) * NCELL + (cell_coord(z)*GS + cell_coord(y))*GS + cell_coord(x);
    atomicAdd(&cnt[g], 1);
}

__global__ __launch_bounds__(1024) void scan_kernel(
        const int* __restrict__ cnt, int* __restrict__ cellstart,
        int* __restrict__ cursor) {
    __shared__ int sums[1024];
    const int tid = threadIdx.x;
    int local[8];
    int s = 0;
#pragma unroll
    for (int j = 0; j < 8; ++j) { local[j] = cnt[tid*8+j]; s += local[j]; }
    sums[tid] = s;
    __syncthreads();
    for (int off = 1; off < 1024; off <<= 1) {
        int v = (tid >= off) ? sums[tid-off] : 0;
        __syncthreads();
        sums[tid] += v;
        __syncthreads();
    }
    int run = sums[tid] - s;
#pragma unroll
    for (int j = 0; j < 8; ++j) {
        cellstart[tid*8+j] = run; cursor[tid*8+j] = run; run += local[j];
    }
    if (tid == 1023) cellstart[2*NCELL] = run;
}

__global__ __launch_bounds__(256) void scatter_kernel(
        const float* __restrict__ coords, int* __restrict__ cursor,
        float4* __restrict__ sorted, int* __restrict__ perm) {
    int t = blockIdx.x * 256 + threadIdx.x;
    float x = coords[(size_t)t*3+0], y = coords[(size_t)t*3+1], z = coords[(size_t)t*3+2];
    int g = (t >> 14) * NCELL + (cell_coord(z)*GS + cell_coord(y))*GS + cell_coord(x);
    int pos = atomicAdd(&cursor[g], 1);
    sorted[pos] = make_float4(x, y, z, __int_as_float(t));
    perm[pos] = t;
}

// ---------------- kNN: block per cell-row, LDS-broadcast scan -------------
__device__ __forceinline__ void ring_off(int R, int s, int& dy, int& dz) {
    if (R == 0) { dy = 0; dz = 0; return; }
    int w = 2*R+1;
    if (s < w)        { dy = -R + s;       dz = -R; }
    else if (s < 2*w) { dy = -R + (s - w); dz =  R; }
    else {
        int rem = s - 2*w;
        if (rem < 2*R-1) { dy = -R; dz = -R+1+rem; }
        else             { dy =  R; dz = -R+1+(rem-(2*R-1)); }
    }
}

#define TOP16_INSERT(d2v, jjv) do {                                   \
    float _d2 = (d2v);                                                \
    if (_d2 < d[KNN-1]) {                                             \
        int _jj = (jjv); bool sa = true;                              \
        _Pragma("unroll")                                             \
        for (int s_ = KNN-1; s_ > 0; --s_) {                          \
            bool sh = _d2 < d[s_-1];                                  \
            float nd = sh ? d[s_-1] : (sa ? _d2 : d[s_]);             \
            int   ni = sh ? id[s_-1] : (sa ? _jj : id[s_]);           \
            d[s_] = nd; id[s_] = ni; sa = sh;                         \
        }                                                             \
        if (sa) { d[0] = _d2; id[0] = _jj; }                          \
    } } while (0)

__global__ __launch_bounds__(256) void knn_rows_kernel(
        const float4* __restrict__ sorted, const int* __restrict__ cellstart,
        float* __restrict__ knn_d2, int* __restrict__ knn_idx) {
    __shared__ __align__(16) float ldsx[256];
    __shared__ __align__(16) float ldsy[256];
    __shared__ __align__(16) float ldsz[256];
    const int t = threadIdx.x;
    const int brow = blockIdx.x;          // 0..511 = cloud*256 + (cz*16+cy)
    const int b  = brow >> 8;
    const int yz = brow & 255;
    const int cy = yz & 15, cz = yz >> 4;
    const int gq = b*NCELL + yz*16;
    const int qstart = cellstart[gq];
    const int qcount = cellstart[gq + GS] - qstart;
    if (qcount <= 0) return;
    const bool active = (t < qcount);
    const float4 q = sorted[qstart + (active ? t : 0)];

    float d[KNN]; int id[KNN];
#pragma unroll
    for (int s = 0; s < KNN; ++s) { d[s] = 3.4e38f; id[s] = 0; }

    for (int R = 0; R < GS; ++R) {
        const int nseg = R ? 8*R : 1;
        for (int s = 0; s < nseg; ++s) {
            int dy, dz;
            ring_off(R, s, dy, dz);
            const int yy = cy + dy, zz = cz + dz;
            if (yy < 0 || yy > GS-1 || zz < 0 || zz > GS-1) continue;
            const int g  = b*NCELL + (zz*GS + yy)*GS;   // slab: full x-row
            const int st = cellstart[g], en = cellstart[g + GS];
            for (int c0 = st; c0 < en; c0 += 256) {
                const int n = min(en - c0, 256);
                const int npad = (n + 3) & ~3;
                __syncthreads();
                if (t < npad) {
                    if (t < n) {
                        float4 c = sorted[c0 + t];
                        ldsx[t] = c.x; ldsy[t] = c.y; ldsz[t] = c.z;
                    } else {
                        ldsx[t] = 1e30f; ldsy[t] = 1e30f; ldsz[t] = 1e30f;
                    }
                }
                __syncthreads();
                if (active) {
                    for (int j = 0; j < npad; j += 4) {
                        const float4 xs = *(const float4*)&ldsx[j];
                        const float4 ys = *(const float4*)&ldsy[j];
                        const float4 zs = *(const float4*)&ldsz[j];
                        { float dx=q.x-xs.x, dy_=q.y-ys.x, dz_=q.z-zs.x;
                          TOP16_INSERT(dx*dx + dy_*dy_ + dz_*dz_, c0+j+0); }
                        { float dx=q.x-xs.y, dy_=q.y-ys.y, dz_=q.z-zs.y;
                          TOP16_INSERT(dx*dx + dy_*dy_ + dz_*dz_, c0+j+1); }
                        { float dx=q.x-xs.z, dy_=q.y-ys.z, dz_=q.z-zs.z;
                          TOP16_INSERT(dx*dx + dy_*dy_ + dz_*dz_, c0+j+2); }
                        { float dx=q.x-xs.w, dy_=q.y-ys.w, dz_=q.z-zs.w;
                          TOP16_INSERT(dx*dx + dy_*dy_ + dz_*dz_, c0+j+3); }
                    }
                }
            }
        }
        // exact bound: nearest unscanned cell is beyond ring R in y/z (x full)
        float bl = 1e30f;
        if (cy - R >= 1)    bl = fminf(bl, q.y - (float)(cy-R)*CELL_H);
        if (cy + R <= GS-2) bl = fminf(bl, (float)(cy+R+1)*CELL_H - q.y);
        if (cz - R >= 1)    bl = fminf(bl, q.z - (float)(cz-R)*CELL_H);
        if (cz + R <= GS-2) bl = fminf(bl, (float)(cz+R+1)*CELL_H - q.z);
        const int mydone = (!active) || (d[KNN-1] <= bl*bl);
        if (__syncthreads_and(mydone)) break;
    }
    if (active) {
        const int o = qstart + t;               // sorted-space output
#pragma unroll
        for (int s = 0; s < KNN; ++s) {
            knn_d2 [(size_t)o*KNN + s] = d[s];
            knn_idx[(size_t)o*KNN + s] = id[s];
        }
    }
}

// ---------------- bf16x2-split MFMA GEMM: C = A @ BT^T (+bias) ------------
__device__ __forceinline__ void pack_split(float4 v, uint2& h, uint2& l) {
    __hip_bfloat16 h0=__float2bfloat16(v.x), h1=__float2bfloat16(v.y),
                   h2=__float2bfloat16(v.z), h3=__float2bfloat16(v.w);
    float r0=v.x-__bfloat162float(h0), r1=v.y-__bfloat162float(h1),
          r2=v.z-__bfloat162float(h2), r3=v.w-__bfloat162float(h3);
    __hip_bfloat16 l0=__float2bfloat16(r0), l1=__float2bfloat16(r1),
                   l2=__float2bfloat16(r2), l3=__float2bfloat16(r3);
    h.x = (unsigned)*(unsigned short*)&h0 | ((unsigned)*(unsigned short*)&h1 << 16);
    h.y = (unsigned)*(unsigned short*)&h2 | ((unsigned)*(unsigned short*)&h3 << 16);
    l.x = (unsigned)*(unsigned short*)&l0 | ((unsigned)*(unsigned short*)&l1 << 16);
    l.y = (unsigned)*(unsigned short*)&l2 | ((unsigned)*(unsigned short*)&l3 << 16);
}

template<int KDIM, bool BIAS, bool GATHER_A, bool SCATTER_OUT>
__global__ __launch_bounds__(256) void gemm_split_kernel(
        const float* __restrict__ A,    // [M][KDIM] fp32
        const float* __restrict__ BT,   // [N][KDIM] fp32
        const float* __restrict__ bias,
        const int*   __restrict__ permA,
        const int*   __restrict__ permOut,
        float* __restrict__ C_, int M, int N) {
    __shared__ unsigned short AsH[128*40], AsL[128*40], BsH[128*40], BsL[128*40];
    const int tid = threadIdx.x;
    const int l = tid & 63, w = tid >> 6;
    const int wm = w >> 1, wn = w & 1;
    const int bm = blockIdx.x * 128, bn = blockIdx.y * 128;
    const f32x4 zero = {0.f, 0.f, 0.f, 0.f};
    f32x4 acc[4][4];
#pragma unroll
    for (int m = 0; m < 4; ++m)
#pragma unroll
        for (int n = 0; n < 4; ++n) acc[m][n] = zero;

    for (int k0 = 0; k0 < KDIM; k0 += 32) {
        __syncthreads();
#pragma unroll
        for (int r2 = 0; r2 < 4; ++r2) {
            int flat = r2*256 + tid;            // 0..1023
            int row = flat >> 3, ke = (flat & 7) * 4;
            int ga = bm + row;
            if (GATHER_A) ga = permA[ga];
            float4 va = *(const float4*)&A[(size_t)ga*KDIM + k0 + ke];
            uint2 uh, ul; pack_split(va, uh, ul);
            *(uint2*)&AsH[row*40 + ke] = uh;
            *(uint2*)&AsL[row*40 + ke] = ul;
            float4 vb = *(const float4*)&BT[(size_t)(bn + row)*KDIM + k0 + ke];
            uint2 vh, vl; pack_split(vb, vh, vl);
            *(uint2*)&BsH[row*40 + ke] = vh;
            *(uint2*)&BsL[row*40 + ke] = vl;
        }
        __syncthreads();
        s16x8 ah[4], al[4], bh[4], bl[4];
        const int ks = (l >> 4) * 8;
#pragma unroll
        for (int m = 0; m < 4; ++m) {
            int r = wm*64 + m*16 + (l & 15);
            ah[m] = *(const s16x8*)&AsH[r*40 + ks];
            al[m] = *(const s16x8*)&AsL[r*40 + ks];
        }
#pragma unroll
        for (int n = 0; n < 4; ++n) {
            int r = wn*64 + n*16 + (l & 15);
            bh[n] = *(const s16x8*)&BsH[r*40 + ks];
            bl[n] = *(const s16x8*)&BsL[r*40 + ks];
        }
#pragma unroll
        for (int m = 0; m < 4; ++m)
#pragma unroll
            for (int n = 0; n < 4; ++n) {
                acc[m][n] = __builtin_amdgcn_mfma_f32_16x16x32_bf16(ah[m], bh[n], acc[m][n], 0, 0, 0);
                acc[m][n] = __builtin_amdgcn_mfma_f32_16x16x32_bf16(ah[m], bl[n], acc[m][n], 0, 0, 0);
                acc[m][n] = __builtin_amdgcn_mfma_f32_16x16x32_bf16(al[m], bh[n], acc[m][n], 0, 0, 0);
            }
    }
#pragma unroll
    for (int m = 0; m < 4; ++m)
#pragma unroll
        for (int n = 0; n < 4; ++n) {
            int ct = bn + wn*64 + n*16 + (l & 15);
            float bv = BIAS ? bias[ct] : 0.f;
#pragma unroll
            for (int j = 0; j < 4; ++j) {
                int rt = bm + wm*64 + m*16 + ((l >> 4) << 2) + j;
                int go = SCATTER_OUT ? permOut[rt] : rt;
                C_[(size_t)go*N + ct] = acc[m][n][j] + bv;
            }
        }
}

// ---------------- softmax weights + weighted relu gather (sorted space) ---
__global__ __launch_bounds__(128) void combine_kernel(
        const float* __restrict__ PQ, const float* __restrict__ knn_d2,
        const int* __restrict__ knn_idx, const float* __restrict__ b1,
        float* __restrict__ hbar) {
    const int n = blockIdx.x;          // sorted position
    const int t = threadIdx.x;
    float dd[KNN];
#pragma unroll
    for (int k = 0; k < KNN; ++k) dd[k] = knn_d2[(size_t)n*KNN + k];
    float m = dd[0];
#pragma unroll
    for (int k = 1; k < KNN; ++k) m = fminf(m, dd[k]);
    float e[KNN]; float sum = 0.f;
#pragma unroll
    for (int k = 0; k < KNN; ++k) { e[k] = __expf(m - dd[k]); sum += e[k]; }
    const float inv = 1.0f / sum;
    const float qv = PQ[(size_t)n*CDIM + IDIM + t];
    const float bb = b1[t];
    float acc = 0.f;
#pragma unroll
    for (int k = 0; k < KNN; ++k) {
        int row = knn_idx[(size_t)n*KNN + k];
        float p = PQ[(size_t)row*CDIM + t];
        acc += e[k] * fmaxf(p - qv + bb, 0.0f);
    }
    hbar[(size_t)n*IDIM + t] = acc * inv;
}

// --------------------------------------------------------------------------
extern "C" void kernel_launch(void* const* d_in, const int* in_sizes, int n_in,
                              void* d_out, int out_size, void* d_ws, size_t ws_size,
                              hipStream_t stream) {
    const float* coords = (const float*)d_in[0];
    const float* feats  = (const float*)d_in[1];
    const float* W1     = (const float*)d_in[2];
    const float* b1     = (const float*)d_in[3];
    const float* W2     = (const float*)d_in[4];
    const float* b2     = (const float*)d_in[5];
    float* out = (float*)d_out;

    char* p = (char*)d_ws;
    float4* sorted = (float4*)p;         p += (size_t)NTOT*16;
    float*  PQ     = (float*)p;          p += (size_t)NTOT*CDIM*4;   // 32MB (sorted order)
    float*  hbar   = (float*)p;          p += (size_t)NTOT*IDIM*4;   // 16MB (sorted order)
    float*  knn_d2 = (float*)p;          p += (size_t)NTOT*KNN*4;
    int*    knn_idx= (int*)p;            p += (size_t)NTOT*KNN*4;
    float*  ABTf   = (float*)p;          p += 65536*4;
    float*  W2Tf   = (float*)p;          p += 32768*4;
    int*    perm   = (int*)p;            p += (size_t)NTOT*4;
    int*    cnt    = (int*)p;            p += 2*NCELL*4;
    int*    cellstart = (int*)p;         p += (2*NCELL+8)*4;
    int*    cursor = (int*)p;            p += 2*NCELL*4;
    // total ~53 MB

    hipMemsetAsync(cnt, 0, 2*NCELL*sizeof(int), stream);
    prep_kernel   <<<384, 256, 0, stream>>>(W1, W2, ABTf, W2Tf);
    count_kernel  <<<NTOT/256, 256, 0, stream>>>(coords, cnt);
    scan_kernel   <<<1, 1024, 0, stream>>>(cnt, cellstart, cursor);
    scatter_kernel<<<NTOT/256, 256, 0, stream>>>(coords, cursor, sorted, perm);
    knn_rows_kernel<<<2*256, 256, 0, stream>>>(sorted, cellstart, knn_d2, knn_idx);
    gemm_split_kernel<CDIM, false, true, false>
        <<<dim3(NTOT/128, 2), 256, 0, stream>>>(
            feats, ABTf, nullptr, perm, nullptr, PQ, NTOT, CDIM);
    combine_kernel<<<NTOT, 128, 0, stream>>>(PQ, knn_d2, knn_idx, b1, hbar);
    gemm_split_kernel<IDIM, true, false, true>
        <<<dim3(NTOT/128, 2), 256, 0, stream>>>(
            hbar, W2Tf, b2, nullptr, perm, out, NTOT, CDIM);
}

// Round 8
// 298.539 us; speedup vs baseline: 7.3684x; 1.2190x over previous
//
#include <hip/hip_runtime.h>
#include <hip/hip_bf16.h>

#define NPTS   16384
#define NCLOUD 2
#define NTOT   (NPTS*NCLOUD)
#define CDIM   256
#define IDIM   128
#define KNN    16
#define GS     16
#define NCELL  (GS*GS*GS)
#define CELL_H 6.25f
#define INV_H  0.16f
#define SLABCAP 256           // max staged points per x-row (P(exceed) ~ 0)

typedef __attribute__((ext_vector_type(8))) short s16x8;
typedef __attribute__((ext_vector_type(4))) float f32x4;

__device__ __forceinline__ int cell_coord(float v) {
    int c = (int)(v * INV_H);
    return c < 0 ? 0 : (c > GS-1 ? GS-1 : c);
}

// ---------------- prep: ABT = [W1_top+W1_bot | W1_bot]^T, W2T --------------
__global__ __launch_bounds__(256) void prep_kernel(
        const float* __restrict__ W1, const float* __restrict__ W2,
        float* __restrict__ ABTf, float* __restrict__ W2Tf) {
    int i = blockIdx.x*256 + threadIdx.x;
    if (i < 65536) {
        int n = i >> 8, k = i & 255;          // ABT[n][k] = AB[k][n]
        float v = (n < IDIM) ? (W1[k*IDIM + n] + W1[(k+CDIM)*IDIM + n])
                             : W1[(k+CDIM)*IDIM + (n-IDIM)];
        ABTf[n*CDIM + k] = v;
    } else {
        int j = i - 65536;                    // W2T[n][k] = W2[k][n]
        int n = j >> 7, k = j & 127;
        W2Tf[n*IDIM + k] = W2[k*CDIM + n];
    }
}

// ---------------- grid build ----------------------------------------------
__global__ __launch_bounds__(256) void count_kernel(
        const float* __restrict__ coords, int* __restrict__ cnt) {
    int t = blockIdx.x * 256 + threadIdx.x;
    float x = coords[(size_t)t*3+0], y = coords[(size_t)t*3+1], z = coords[(size_t)t*3+2];
    int g = (t >> 14) * NCELL + (cell_coord(z)*GS + cell_coord(y))*GS + cell_coord(x);
    atomicAdd(&cnt[g], 1);
}

__global__ __launch_bounds__(1024) void scan_kernel(
        const int* __restrict__ cnt, int* __restrict__ cellstart,
        int* __restrict__ cursor) {
    __shared__ int sums[1024];
    const int tid = threadIdx.x;
    int local[8];
    int s = 0;
#pragma unroll
    for (int j = 0; j < 8; ++j) { local[j] = cnt[tid*8+j]; s += local[j]; }
    sums[tid] = s;
    __syncthreads();
    for (int off = 1; off < 1024; off <<= 1) {
        int v = (tid >= off) ? sums[tid-off] : 0;
        __syncthreads();
        sums[tid] += v;
        __syncthreads();
    }
    int run = sums[tid] - s;
#pragma unroll
    for (int j = 0; j < 8; ++j) {
        cellstart[tid*8+j] = run; cursor[tid*8+j] = run; run += local[j];
    }
    if (tid == 1023) cellstart[2*NCELL] = run;
}

__global__ __launch_bounds__(256) void scatter_kernel(
        const float* __restrict__ coords, int* __restrict__ cursor,
        float4* __restrict__ sorted, int* __restrict__ perm) {
    int t = blockIdx.x * 256 + threadIdx.x;
    float x = coords[(size_t)t*3+0], y = coords[(size_t)t*3+1], z = coords[(size_t)t*3+2];
    int g = (t >> 14) * NCELL + (cell_coord(z)*GS + cell_coord(y))*GS + cell_coord(x);
    int pos = atomicAdd(&cursor[g], 1);
    sorted[pos] = make_float4(x, y, z, __int_as_float(t));
    perm[pos] = t;
}

// ---------------- kNN: 1-wave blocks, per-lane x-window -------------------
__device__ __forceinline__ void ring_off(int R, int s, int& dy, int& dz) {
    if (R == 0) { dy = 0; dz = 0; return; }
    int w = 2*R+1;
    if (s < w)        { dy = -R + s;       dz = -R; }
    else if (s < 2*w) { dy = -R + (s - w); dz =  R; }
    else {
        int rem = s - 2*w;
        if (rem < 2*R-1) { dy = -R; dz = -R+1+rem; }
        else             { dy =  R; dz = -R+1+(rem-(2*R-1)); }
    }
}

#define TOP16_INSERT(d2v, jjv) do {                                   \
    float _d2 = (d2v);                                                \
    if (_d2 < d[KNN-1]) {                                             \
        int _jj = (jjv); bool sa = true;                              \
        _Pragma("unroll")                                             \
        for (int s_ = KNN-1; s_ > 0; --s_) {                          \
            bool sh = _d2 < d[s_-1];                                  \
            float nd = sh ? d[s_-1] : (sa ? _d2 : d[s_]);             \
            int   ni = sh ? id[s_-1] : (sa ? _jj : id[s_]);           \
            d[s_] = nd; id[s_] = ni; sa = sh;                         \
        }                                                             \
        if (sa) { d[0] = _d2; id[0] = _jj; }                          \
    } } while (0)

__global__ __launch_bounds__(64) void knn_win_kernel(
        const float4* __restrict__ sorted, const int* __restrict__ cellstart,
        float* __restrict__ knn_d2, int* __restrict__ knn_idx) {
    __shared__ float ldsx[SLABCAP], ldsy[SLABCAP], ldsz[SLABCAP];
    __shared__ int cellofs[GS+1];
    const int t = threadIdx.x;
    const int bid = blockIdx.x;            // (row, chunk): 0..1023
    const int brow = bid >> 1, chunk = bid & 1;
    const int b  = brow >> 8;
    const int yz = brow & 255;
    const int cy = yz & 15, cz = yz >> 4;
    const int gq = b*NCELL + yz*16;
    const int qstart = cellstart[gq];
    const int qcount = cellstart[gq + GS] - qstart;

    for (int q0 = chunk*64; q0 < qcount; q0 += 64) {
        const bool active = (q0 + t < qcount);
        const float4 q = sorted[qstart + (active ? q0 + t : 0)];
        const int cx = cell_coord(q.x);
        const int wlo = cx-2 < 0 ? 0 : cx-2;
        const int whi = cx+2 > GS-1 ? GS-1 : cx+2;

        float d[KNN]; int id[KNN];
#pragma unroll
        for (int s = 0; s < KNN; ++s) { d[s] = 3.4e38f; id[s] = 0; }
        bool fin = !active;
        bool alldone = false;

        for (int phase = 0; phase < 2 && !alldone; ++phase) {
            for (int R = 0; R < GS && !alldone; ++R) {
                const int nseg = R ? 8*R : 1;
                for (int s = 0; s < nseg; ++s) {
                    int dy, dz;
                    ring_off(R, s, dy, dz);
                    const int yy = cy + dy, zz = cz + dz;
                    if (yy < 0 || yy > GS-1 || zz < 0 || zz > GS-1) continue;
                    const int g  = b*NCELL + (zz*GS + yy)*GS;
                    const int st = cellstart[g];
                    int n = cellstart[g + GS] - st;
                    if (n > SLABCAP) n = SLABCAP;
                    __syncthreads();
                    if (t < GS+1) {
                        int v = cellstart[g + t] - st;
                        cellofs[t] = v > n ? n : v;
                    }
                    for (int i = t; i < n; i += 64) {
                        float4 c = sorted[st + i];
                        ldsx[i] = c.x; ldsy[i] = c.y; ldsz[i] = c.z;
                    }
                    __syncthreads();
                    if (!fin) {
                        const int lo = cellofs[wlo], hi = cellofs[whi+1];
                        if (phase == 0) {
                            for (int e = lo; e < hi; ++e) {
                                float dx = q.x-ldsx[e], dy_ = q.y-ldsy[e], dz_ = q.z-ldsz[e];
                                TOP16_INSERT(dx*dx + dy_*dy_ + dz_*dz_, st + e);
                            }
                        } else {
                            // complement of the phase-0 window (no duplicates)
                            for (int e = 0; e < n; ++e) {
                                if (e >= lo && e < hi) continue;
                                float dx = q.x-ldsx[e], dy_ = q.y-ldsy[e], dz_ = q.z-ldsz[e];
                                TOP16_INSERT(dx*dx + dy_*dy_ + dz_*dz_, st + e);
                            }
                        }
                    }
                }
                // exact bound: nearest UNSCANNED geometry
                float bl = 1e30f;
                if (cy - R >= 1)    bl = fminf(bl, q.y - (float)(cy-R)*CELL_H);
                if (cy + R <= GS-2) bl = fminf(bl, (float)(cy+R+1)*CELL_H - q.y);
                if (cz - R >= 1)    bl = fminf(bl, q.z - (float)(cz-R)*CELL_H);
                if (cz + R <= GS-2) bl = fminf(bl, (float)(cz+R+1)*CELL_H - q.z);
                if (phase == 0) {   // x-window faces (x only partially scanned)
                    if (cx - 2 >= 1)    bl = fminf(bl, q.x - (float)(cx-2)*CELL_H);
                    if (cx + 2 <= GS-2) bl = fminf(bl, (float)(cx+3)*CELL_H - q.x);
                }
                fin = fin || (d[KNN-1] <= bl*bl);
                alldone = __syncthreads_and((int)fin);
            }
        }
        if (active) {
            const int o = qstart + q0 + t;      // sorted-space output
#pragma unroll
            for (int s = 0; s < KNN; ++s) {
                knn_d2 [(size_t)o*KNN + s] = d[s];
                knn_idx[(size_t)o*KNN + s] = id[s];
            }
        }
        if (chunk == 0) break;                   // chunk 0 only does [0,64)
    }
}

// ---------------- bf16x2-split MFMA GEMM: C = A @ BT^T (+bias) ------------
__device__ __forceinline__ void pack_split(float4 v, uint2& h, uint2& l) {
    __hip_bfloat16 h0=__float2bfloat16(v.x), h1=__float2bfloat16(v.y),
                   h2=__float2bfloat16(v.z), h3=__float2bfloat16(v.w);
    float r0=v.x-__bfloat162float(h0), r1=v.y-__bfloat162float(h1),
          r2=v.z-__bfloat162float(h2), r3=v.w-__bfloat162float(h3);
    __hip_bfloat16 l0=__float2bfloat16(r0), l1=__float2bfloat16(r1),
                   l2=__float2bfloat16(r2), l3=__float2bfloat16(r3);
    h.x = (unsigned)*(unsigned short*)&h0 | ((unsigned)*(unsigned short*)&h1 << 16);
    h.y = (unsigned)*(unsigned short*)&h2 | ((unsigned)*(unsigned short*)&h3 << 16);
    l.x = (unsigned)*(unsigned short*)&l0 | ((unsigned)*(unsigned short*)&l1 << 16);
    l.y = (unsigned)*(unsigned short*)&l2 | ((unsigned)*(unsigned short*)&l3 << 16);
}

template<int KDIM, bool BIAS, bool GATHER_A, bool SCATTER_OUT>
__global__ __launch_bounds__(256) void gemm_split_kernel(
        const float* __restrict__ A,    // [M][KDIM] fp32
        const float* __restrict__ BT,   // [N][KDIM] fp32
        const float* __restrict__ bias,
        const int*   __restrict__ permA,
        const int*   __restrict__ permOut,
        float* __restrict__ C_, int M, int N) {
    __shared__ unsigned short AsH[128*40], AsL[128*40], BsH[128*40], BsL[128*40];
    const int tid = threadIdx.x;
    const int l = tid & 63, w = tid >> 6;
    const int wm = w >> 1, wn = w & 1;
    const int bm = blockIdx.x * 128, bn = blockIdx.y * 128;
    const f32x4 zero = {0.f, 0.f, 0.f, 0.f};
    f32x4 acc[4][4];
#pragma unroll
    for (int m = 0; m < 4; ++m)
#pragma unroll
        for (int n = 0; n < 4; ++n) acc[m][n] = zero;

    for (int k0 = 0; k0 < KDIM; k0 += 32) {
        __syncthreads();
#pragma unroll
        for (int r2 = 0; r2 < 4; ++r2) {
            int flat = r2*256 + tid;            // 0..1023
            int row = flat >> 3, ke = (flat & 7) * 4;
            int ga = bm + row;
            if (GATHER_A) ga = permA[ga];
            float4 va = *(const float4*)&A[(size_t)ga*KDIM + k0 + ke];
            uint2 uh, ul; pack_split(va, uh, ul);
            *(uint2*)&AsH[row*40 + ke] = uh;
            *(uint2*)&AsL[row*40 + ke] = ul;
            float4 vb = *(const float4*)&BT[(size_t)(bn + row)*KDIM + k0 + ke];
            uint2 vh, vl; pack_split(vb, vh, vl);
            *(uint2*)&BsH[row*40 + ke] = vh;
            *(uint2*)&BsL[row*40 + ke] = vl;
        }
        __syncthreads();
        s16x8 ah[4], al[4], bh[4], bl[4];
        const int ks = (l >> 4) * 8;
#pragma unroll
        for (int m = 0; m < 4; ++m) {
            int r = wm*64 + m*16 + (l & 15);
            ah[m] = *(const s16x8*)&AsH[r*40 + ks];
            al[m] = *(const s16x8*)&AsL[r*40 + ks];
        }
#pragma unroll
        for (int n = 0; n < 4; ++n) {
            int r = wn*64 + n*16 + (l & 15);
            bh[n] = *(const s16x8*)&BsH[r*40 + ks];
            bl[n] = *(const s16x8*)&BsL[r*40 + ks];
        }
#pragma unroll
        for (int m = 0; m < 4; ++m)
#pragma unroll
            for (int n = 0; n < 4; ++n) {
                acc[m][n] = __builtin_amdgcn_mfma_f32_16x16x32_bf16(ah[m], bh[n], acc[m][n], 0, 0, 0);
                acc[m][n] = __builtin_amdgcn_mfma_f32_16x16x32_bf16(ah[m], bl[n], acc[m][n], 0, 0, 0);
                acc[m][n] = __builtin_amdgcn_mfma_f32_16x16x32_bf16(al[m], bh[n], acc[m][n], 0, 0, 0);
            }
    }
#pragma unroll
    for (int m = 0; m < 4; ++m)
#pragma unroll
        for (int n = 0; n < 4; ++n) {
            int ct = bn + wn*64 + n*16 + (l & 15);
            float bv = BIAS ? bias[ct] : 0.f;
#pragma unroll
            for (int j = 0; j < 4; ++j) {
                int rt = bm + wm*64 + m*16 + ((l >> 4) << 2) + j;
                int go = SCATTER_OUT ? permOut[rt] : rt;
                C_[(size_t)go*N + ct] = acc[m][n][j] + bv;
            }
        }
}

// ---------------- softmax weights + weighted relu gather (sorted space) ---
__global__ __launch_bounds__(128) void combine_kernel(
        const float* __restrict__ PQ, const float* __restrict__ knn_d2,
        const int* __restrict__ knn_idx, const float* __restrict__ b1,
        float* __restrict__ hbar) {
    const int n = blockIdx.x;          // sorted position
    const int t = threadIdx.x;
    float dd[KNN];
#pragma unroll
    for (int k = 0; k < KNN; ++k) dd[k] = knn_d2[(size_t)n*KNN + k];
    float m = dd[0];
#pragma unroll
    for (int k = 1; k < KNN; ++k) m = fminf(m, dd[k]);
    float e[KNN]; float sum = 0.f;
#pragma unroll
    for (int k = 0; k < KNN; ++k) { e[k] = __expf(m - dd[k]); sum += e[k]; }
    const float inv = 1.0f / sum;
    const float qv = PQ[(size_t)n*CDIM + IDIM + t];
    const float bb = b1[t];
    float acc = 0.f;
#pragma unroll
    for (int k = 0; k < KNN; ++k) {
        int row = knn_idx[(size_t)n*KNN + k];
        float p = PQ[(size_t)row*CDIM + t];
        acc += e[k] * fmaxf(p - qv + bb, 0.0f);
    }
    hbar[(size_t)n*IDIM + t] = acc * inv;
}

// --------------------------------------------------------------------------
extern "C" void kernel_launch(void* const* d_in, const int* in_sizes, int n_in,
                              void* d_out, int out_size, void* d_ws, size_t ws_size,
                              hipStream_t stream) {
    const float* coords = (const float*)d_in[0];
    const float* feats  = (const float*)d_in[1];
    const float* W1     = (const float*)d_in[2];
    const float* b1     = (const float*)d_in[3];
    const float* W2     = (const float*)d_in[4];
    const float* b2     = (const float*)d_in[5];
    float* out = (float*)d_out;

    char* p = (char*)d_ws;
    float4* sorted = (float4*)p;         p += (size_t)NTOT*16;
    float*  PQ     = (float*)p;          p += (size_t)NTOT*CDIM*4;   // 32MB (sorted order)
    float*  hbar   = (float*)p;          p += (size_t)NTOT*IDIM*4;   // 16MB (sorted order)
    float*  knn_d2 = (float*)p;          p += (size_t)NTOT*KNN*4;
    int*    knn_idx= (int*)p;            p += (size_t)NTOT*KNN*4;
    float*  ABTf   = (float*)p;          p += 65536*4;
    float*  W2Tf   = (float*)p;          p += 32768*4;
    int*    perm   = (int*)p;            p += (size_t)NTOT*4;
    int*    cnt    = (int*)p;            p += 2*NCELL*4;
    int*    cellstart = (int*)p;         p += (2*NCELL+8)*4;
    int*    cursor = (int*)p;            p += 2*NCELL*4;
    // total ~53 MB

    hipMemsetAsync(cnt, 0, 2*NCELL*sizeof(int), stream);
    prep_kernel   <<<384, 256, 0, stream>>>(W1, W2, ABTf, W2Tf);
    count_kernel  <<<NTOT/256, 256, 0, stream>>>(coords, cnt);
    scan_kernel   <<<1, 1024, 0, stream>>>(cnt, cellstart, cursor);
    scatter_kernel<<<NTOT/256, 256, 0, stream>>>(coords, cursor, sorted, perm);
    knn_win_kernel<<<2*256*2, 64, 0, stream>>>(sorted, cellstart, knn_d2, knn_idx);
    gemm_split_kernel<CDIM, false, true, false>
        <<<dim3(NTOT/128, 2), 256, 0, stream>>>(
            feats, ABTf, nullptr, perm, nullptr, PQ, NTOT, CDIM);
    combine_kernel<<<NTOT, 128, 0, stream>>>(PQ, knn_d2, knn_idx, b1, hbar);
    gemm_split_kernel<IDIM, true, false, true>
        <<<dim3(NTOT/128, 2), 256, 0, stream>>>(
            hbar, W2Tf, b2, nullptr, perm, out, NTOT, CDIM);
}

// Round 11
// 256.170 us; speedup vs baseline: 8.5871x; 1.1654x over previous
//
#include <hip/hip_runtime.h>
#include <hip/hip_bf16.h>

#define NPTS   16384
#define NCLOUD 2
#define NTOT   (NPTS*NCLOUD)
#define CDIM   256
#define IDIM   128
#define KNN    16
#define GS     16
#define NCELL  (GS*GS*GS)
#define CELL_H 6.25f
#define INV_H  0.16f
#define REGCAP 2048           // staged-region capacity (~1600 expected, P(>2048)~e^-60)

typedef __attribute__((ext_vector_type(8))) short s16x8;
typedef __attribute__((ext_vector_type(4))) float f32x4;

__device__ __forceinline__ int cell_coord(float v) {
    int c = (int)(v * INV_H);
    return c < 0 ? 0 : (c > GS-1 ? GS-1 : c);
}

// ---------------- prep: ABT = [W1_top+W1_bot | W1_bot]^T, W2T --------------
__global__ __launch_bounds__(256) void prep_kernel(
        const float* __restrict__ W1, const float* __restrict__ W2,
        float* __restrict__ ABTf, float* __restrict__ W2Tf) {
    int i = blockIdx.x*256 + threadIdx.x;
    if (i < 65536) {
        int n = i >> 8, k = i & 255;          // ABT[n][k] = AB[k][n]
        float v = (n < IDIM) ? (W1[k*IDIM + n] + W1[(k+CDIM)*IDIM + n])
                             : W1[(k+CDIM)*IDIM + (n-IDIM)];
        ABTf[n*CDIM + k] = v;
    } else {
        int j = i - 65536;                    // W2T[n][k] = W2[k][n]
        int n = j >> 7, k = j & 127;
        W2Tf[n*IDIM + k] = W2[k*CDIM + n];
    }
}

// ---------------- grid build ----------------------------------------------
__global__ __launch_bounds__(256) void count_kernel(
        const float* __restrict__ coords, int* __restrict__ cnt) {
    int t = blockIdx.x * 256 + threadIdx.x;
    float x = coords[(size_t)t*3+0], y = coords[(size_t)t*3+1], z = coords[(size_t)t*3+2];
    int g = (t >> 14) * NCELL + (cell_coord(z)*GS + cell_coord(y))*GS + cell_coord(x);
    atomicAdd(&cnt[g], 1);
}

__global__ __launch_bounds__(1024) void scan_kernel(
        const int* __restrict__ cnt, int* __restrict__ cellstart,
        int* __restrict__ cursor) {
    __shared__ int sums[1024];
    const int tid = threadIdx.x;
    int local[8];
    int s = 0;
#pragma unroll
    for (int j = 0; j < 8; ++j) { local[j] = cnt[tid*8+j]; s += local[j]; }
    sums[tid] = s;
    __syncthreads();
    for (int off = 1; off < 1024; off <<= 1) {
        int v = (tid >= off) ? sums[tid-off] : 0;
        __syncthreads();
        sums[tid] += v;
        __syncthreads();
    }
    int run = sums[tid] - s;
#pragma unroll
    for (int j = 0; j < 8; ++j) {
        cellstart[tid*8+j] = run; cursor[tid*8+j] = run; run += local[j];
    }
    if (tid == 1023) cellstart[2*NCELL] = run;
}

__global__ __launch_bounds__(256) void scatter_kernel(
        const float* __restrict__ coords, int* __restrict__ cursor,
        float4* __restrict__ sorted, int* __restrict__ perm) {
    int t = blockIdx.x * 256 + threadIdx.x;
    float x = coords[(size_t)t*3+0], y = coords[(size_t)t*3+1], z = coords[(size_t)t*3+2];
    int g = (t >> 14) * NCELL + (cell_coord(z)*GS + cell_coord(y))*GS + cell_coord(x);
    int pos = atomicAdd(&cursor[g], 1);
    sorted[pos] = make_float4(x, y, z, __int_as_float(t));
    perm[pos] = t;
}

// ---------------- kNN: region-staged, 4 lanes/query -----------------------
#define TOP16_INSERT(d2v, jjv) do {                                   \
    float _d2 = (d2v);                                                \
    if (_d2 < d[KNN-1]) {                                             \
        int _jj = (jjv); bool sa = true;                              \
        _Pragma("unroll")                                             \
        for (int s_ = KNN-1; s_ > 0; --s_) {                          \
            bool sh = _d2 < d[s_-1];                                  \
            float nd = sh ? d[s_-1] : (sa ? _d2 : d[s_]);             \
            int   ni = sh ? id[s_-1] : (sa ? _jj : id[s_]);           \
            d[s_] = nd; id[s_] = ni; sa = sh;                         \
        }                                                             \
        if (sa) { d[0] = _d2; id[0] = _jj; }                          \
    } } while (0)

__global__ __launch_bounds__(256) void knn_region_kernel(
        const float4* __restrict__ sorted, const int* __restrict__ cellstart,
        float* __restrict__ knn_d2, int* __restrict__ knn_idx) {
    __shared__ float rx[REGCAP], ry[REGCAP], rz[REGCAP];
    __shared__ int cofs[25][17];     // region offset of cell (row r, x k)
    __shared__ int rstart[25];       // sorted-space start of row r
    __shared__ int segmeta[8];       // [0..4]=seg base, [5]=total, [6]=overflow
    const int t = threadIdx.x;
    const int bid = blockIdx.x;
    const int brow = bid >> 1, chunk = bid & 1;
    const int b  = brow >> 8;
    const int yz = brow & 255;
    const int cy = yz & 15, cz = yz >> 4;
    const int gq = b*NCELL + yz*16;
    const int qstart = cellstart[gq];
    const int qcount = cellstart[gq + GS] - qstart;
    if (qcount <= 0) return;
    if (chunk == 1 && qcount <= 64) return;

    const int ylo = cy-2 < 0 ? 0 : cy-2, yhi = cy+2 > 15 ? 15 : cy+2;

    int q0 = chunk ? 64 : 0;
    while (true) {
        // ---- stage R<=2 region: 5 contiguous segments (one per dz) ----
        __syncthreads();                      // protect LDS reuse
        if (t == 0) {
            int base = 0;
            for (int dzi = 0; dzi < 5; ++dzi) {
                segmeta[dzi] = base;
                int zz = cz + dzi - 2;
                if (zz >= 0 && zz <= 15) {
                    int s0 = cellstart[b*NCELL + (zz*16 + ylo)*16];
                    int e0 = cellstart[b*NCELL + (zz*16 + yhi)*16 + 16];
                    base += e0 - s0;
                }
            }
            segmeta[5] = base;
            segmeta[6] = (base > REGCAP) ? 1 : 0;
        }
        __syncthreads();
        const bool overflow = (segmeta[6] != 0);
        for (int i = t; i < 425; i += 256) {  // cofs + rstart
            int r = i / 17, k = i % 17;
            int dzi = r / 5, dyi = r % 5;
            int zz = cz + dzi - 2, yy = cy + dyi - 2;
            int v = 0, rs = 0;
            if (zz >= 0 && zz <= 15 && yy >= 0 && yy <= 15) {
                int segs = cellstart[b*NCELL + (zz*16 + ylo)*16];
                int rowg = b*NCELL + (zz*16 + yy)*16;
                v = segmeta[dzi] + (cellstart[rowg + k] - segs);
                if (v > REGCAP) v = REGCAP;
                rs = cellstart[rowg];
            }
            cofs[r][k] = v;
            if (k == 0) rstart[r] = rs;
        }
        if (!overflow) {
            for (int dzi = 0; dzi < 5; ++dzi) {
                int zz = cz + dzi - 2;
                if (zz < 0 || zz > 15) continue;
                int s0  = cellstart[b*NCELL + (zz*16 + ylo)*16];
                int len = cellstart[b*NCELL + (zz*16 + yhi)*16 + 16] - s0;
                int dst = segmeta[dzi];
                for (int i = t; i < len; i += 256) {
                    float4 c = sorted[s0 + i];
                    rx[dst+i] = c.x; ry[dst+i] = c.y; rz[dst+i] = c.z;
                }
            }
        }
        __syncthreads();

        // ---- phase 1: 4 lanes per query over per-query x-window ----
        const int w = t >> 6, lane = t & 63;
        const int sub = lane >> 4, qi = lane & 15;
        const int qidx = q0 + w*16 + qi;
        const bool active = (qidx < qcount);
        const float4 q = sorted[qstart + (active ? qidx : 0)];
        const int cx = cell_coord(q.x);
        const int wlo = cx-2 < 0 ? 0 : cx-2, whi = cx+2 > 15 ? 15 : cx+2;

        float d[KNN]; int id[KNN];
#pragma unroll
        for (int s_ = 0; s_ < KNN; ++s_) { d[s_] = 3.4e38f; id[s_] = 0; }
        bool fin = !active;

        if (!overflow) {
            if (active) {
                for (int r = 0; r < 25; ++r) {
                    const int lo = cofs[r][wlo], hi = cofs[r][whi+1];
                    const int base0 = cofs[r][0], rs = rstart[r];
                    for (int e = lo + sub; e < hi; e += 4) {
                        float dx = q.x - rx[e], dy = q.y - ry[e], dz = q.z - rz[e];
                        TOP16_INSERT(dx*dx + dy*dy + dz*dz, rs + (e - base0));
                    }
                }
            }
            // merge the 4 sub-lists via shfl_xor butterfly.
            // CRITICAL: snapshot the partner's ENTIRE list BEFORE inserting —
            // inserting while exchanging reads partner entries that the
            // partner has already overwritten with OUR values (round-8 bug:
            // duplicate/dropped neighbors, absmax 0.268).
#pragma unroll
        for (int mask = 16; mask <= 32; mask <<= 1) {
                float od[KNN]; int oi[KNN];
#pragma unroll
                for (int j = 0; j < KNN; ++j) {
                    od[j] = __shfl_xor(d[j], mask);
                    oi[j] = __shfl_xor(id[j], mask);
                }
                if (active) {
#pragma unroll
                    for (int j = 0; j < KNN; ++j) TOP16_INSERT(od[j], oi[j]);
                }
            }
            // exact bound: nearest unscanned face of the region
            float bl = 1e30f;
            if (cx-2 >= 1)  bl = fminf(bl, q.x - (float)(cx-2)*CELL_H);
            if (cx+2 <= 14) bl = fminf(bl, (float)(cx+3)*CELL_H - q.x);
            if (cy-2 >= 1)  bl = fminf(bl, q.y - (float)(cy-2)*CELL_H);
            if (cy+2 <= 14) bl = fminf(bl, (float)(cy+3)*CELL_H - q.y);
            if (cz-2 >= 1)  bl = fminf(bl, q.z - (float)(cz-2)*CELL_H);
            if (cz+2 <= 14) bl = fminf(bl, (float)(cz+3)*CELL_H - q.z);
            fin = fin || (d[KNN-1] <= bl*bl);
        }

        if (__syncthreads_and((int)fin)) {
            if (active && sub == 0) {
                const size_t o = (size_t)(qstart + qidx) * KNN;
#pragma unroll
                for (int s_ = 0; s_ < KNN; ++s_) {
                    knn_d2[o + s_] = d[s_]; knn_idx[o + s_] = id[s_];
                }
            }
        } else {
            // ---- fallback (P ~ 1e-35 / overflow): brute-force whole cloud ----
            const int fqi = q0 + t;
            const bool fact = (t < 64) && (fqi < qcount);
            const float4 fq = sorted[qstart + (fact ? fqi : 0)];
#pragma unroll
            for (int s_ = 0; s_ < KNN; ++s_) { d[s_] = 3.4e38f; id[s_] = 0; }
            const int cbase = b * NPTS;
            for (int c0 = 0; c0 < NPTS; c0 += 256) {
                __syncthreads();
                float4 c = sorted[cbase + c0 + t];
                rx[t] = c.x; ry[t] = c.y; rz[t] = c.z;
                __syncthreads();
                if (fact) {
                    for (int j = 0; j < 256; ++j) {
                        float dx = fq.x - rx[j], dy = fq.y - ry[j], dz = fq.z - rz[j];
                        TOP16_INSERT(dx*dx + dy*dy + dz*dz, cbase + c0 + j);
                    }
                }
            }
            if (fact) {
                const size_t o = (size_t)(qstart + fqi) * KNN;
#pragma unroll
                for (int s_ = 0; s_ < KNN; ++s_) {
                    knn_d2[o + s_] = d[s_]; knn_idx[o + s_] = id[s_];
                }
            }
        }
        if (chunk == 0) break;
        q0 += 64;
        if (q0 >= qcount) break;
    }
}

// ---------------- bf16x2-split MFMA GEMM: C = A @ BT^T (+bias) ------------
__device__ __forceinline__ void pack_split(float4 v, uint2& h, uint2& l) {
    __hip_bfloat16 h0=__float2bfloat16(v.x), h1=__float2bfloat16(v.y),
                   h2=__float2bfloat16(v.z), h3=__float2bfloat16(v.w);
    float r0=v.x-__bfloat162float(h0), r1=v.y-__bfloat162float(h1),
          r2=v.z-__bfloat162float(h2), r3=v.w-__bfloat162float(h3);
    __hip_bfloat16 l0=__float2bfloat16(r0), l1=__float2bfloat16(r1),
                   l2=__float2bfloat16(r2), l3=__float2bfloat16(r3);
    h.x = (unsigned)*(unsigned short*)&h0 | ((unsigned)*(unsigned short*)&h1 << 16);
    h.y = (unsigned)*(unsigned short*)&h2 | ((unsigned)*(unsigned short*)&h3 << 16);
    l.x = (unsigned)*(unsigned short*)&l0 | ((unsigned)*(unsigned short*)&l1 << 16);
    l.y = (unsigned)*(unsigned short*)&l2 | ((unsigned)*(unsigned short*)&l3 << 16);
}

template<int KDIM, bool BIAS, bool GATHER_A, bool SCATTER_OUT>
__global__ __launch_bounds__(256) void gemm_split_kernel(
        const float* __restrict__ A,    // [M][KDIM] fp32
        const float* __restrict__ BT,   // [N][KDIM] fp32
        const float* __restrict__ bias,
        const int*   __restrict__ permA,
        const int*   __restrict__ permOut,
        float* __restrict__ C_, int M, int N) {
    __shared__ unsigned short AsH[128*40], AsL[128*40], BsH[128*40], BsL[128*40];
    const int tid = threadIdx.x;
    const int l = tid & 63, w = tid >> 6;
    const int wm = w >> 1, wn = w & 1;
    const int bm = blockIdx.x * 128, bn = blockIdx.y * 128;
    const f32x4 zero = {0.f, 0.f, 0.f, 0.f};
    f32x4 acc[4][4];
#pragma unroll
    for (int m = 0; m < 4; ++m)
#pragma unroll
        for (int n = 0; n < 4; ++n) acc[m][n] = zero;

    for (int k0 = 0; k0 < KDIM; k0 += 32) {
        __syncthreads();
#pragma unroll
        for (int r2 = 0; r2 < 4; ++r2) {
            int flat = r2*256 + tid;            // 0..1023
            int row = flat >> 3, ke = (flat & 7) * 4;
            int ga = bm + row;
            if (GATHER_A) ga = permA[ga];
            float4 va = *(const float4*)&A[(size_t)ga*KDIM + k0 + ke];
            uint2 uh, ul; pack_split(va, uh, ul);
            *(uint2*)&AsH[row*40 + ke] = uh;
            *(uint2*)&AsL[row*40 + ke] = ul;
            float4 vb = *(const float4*)&BT[(size_t)(bn + row)*KDIM + k0 + ke];
            uint2 vh, vl; pack_split(vb, vh, vl);
            *(uint2*)&BsH[row*40 + ke] = vh;
            *(uint2*)&BsL[row*40 + ke] = vl;
        }
        __syncthreads();
        s16x8 ah[4], al[4], bh[4], bl[4];
        const int ks = (l >> 4) * 8;
#pragma unroll
        for (int m = 0; m < 4; ++m) {
            int r = wm*64 + m*16 + (l & 15);
            ah[m] = *(const s16x8*)&AsH[r*40 + ks];
            al[m] = *(const s16x8*)&AsL[r*40 + ks];
        }
#pragma unroll
        for (int n = 0; n < 4; ++n) {
            int r = wn*64 + n*16 + (l & 15);
            bh[n] = *(const s16x8*)&BsH[r*40 + ks];
            bl[n] = *(const s16x8*)&BsL[r*40 + ks];
        }
#pragma unroll
        for (int m = 0; m < 4; ++m)
#pragma unroll
            for (int n = 0; n < 4; ++n) {
                acc[m][n] = __builtin_amdgcn_mfma_f32_16x16x32_bf16(ah[m], bh[n], acc[m][n], 0, 0, 0);
                acc[m][n] = __builtin_amdgcn_mfma_f32_16x16x32_bf16(ah[m], bl[n], acc[m][n], 0, 0, 0);
                acc[m][n] = __builtin_amdgcn_mfma_f32_16x16x32_bf16(al[m], bh[n], acc[m][n], 0, 0, 0);
            }
    }
#pragma unroll
    for (int m = 0; m < 4; ++m)
#pragma unroll
        for (int n = 0; n < 4; ++n) {
            int ct = bn + wn*64 + n*16 + (l & 15);
            float bv = BIAS ? bias[ct] : 0.f;
#pragma unroll
            for (int j = 0; j < 4; ++j) {
                int rt = bm + wm*64 + m*16 + ((l >> 4) << 2) + j;
                int go = SCATTER_OUT ? permOut[rt] : rt;
                C_[(size_t)go*N + ct] = acc[m][n][j] + bv;
            }
        }
}

// ---------------- softmax weights + weighted relu gather (sorted space) ---
__global__ __launch_bounds__(128) void combine_kernel(
        const float* __restrict__ PQ, const float* __restrict__ knn_d2,
        const int* __restrict__ knn_idx, const float* __restrict__ b1,
        float* __restrict__ hbar) {
    const int n = blockIdx.x;          // sorted position
    const int t = threadIdx.x;
    float dd[KNN];
#pragma unroll
    for (int k = 0; k < KNN; ++k) dd[k] = knn_d2[(size_t)n*KNN + k];
    float m = dd[0];
#pragma unroll
    for (int k = 1; k < KNN; ++k) m = fminf(m, dd[k]);
    float e[KNN]; float sum = 0.f;
#pragma unroll
    for (int k = 0; k < KNN; ++k) { e[k] = __expf(m - dd[k]); sum += e[k]; }
    const float inv = 1.0f / sum;
    const float qv = PQ[(size_t)n*CDIM + IDIM + t];
    const float bb = b1[t];
    float acc = 0.f;
#pragma unroll
    for (int k = 0; k < KNN; ++k) {
        int row = knn_idx[(size_t)n*KNN + k];
        float p = PQ[(size_t)row*CDIM + t];
        acc += e[k] * fmaxf(p - qv + bb, 0.0f);
    }
    hbar[(size_t)n*IDIM + t] = acc * inv;
}

// --------------------------------------------------------------------------
extern "C" void kernel_launch(void* const* d_in, const int* in_sizes, int n_in,
                              void* d_out, int out_size, void* d_ws, size_t ws_size,
                              hipStream_t stream) {
    const float* coords = (const float*)d_in[0];
    const float* feats  = (const float*)d_in[1];
    const float* W1     = (const float*)d_in[2];
    const float* b1     = (const float*)d_in[3];
    const float* W2     = (const float*)d_in[4];
    const float* b2     = (const float*)d_in[5];
    float* out = (float*)d_out;

    char* p = (char*)d_ws;
    float4* sorted = (float4*)p;         p += (size_t)NTOT*16;
    float*  PQ     = (float*)p;          p += (size_t)NTOT*CDIM*4;   // 32MB (sorted order)
    float*  hbar   = (float*)p;          p += (size_t)NTOT*IDIM*4;   // 16MB (sorted order)
    float*  knn_d2 = (float*)p;          p += (size_t)NTOT*KNN*4;
    int*    knn_idx= (int*)p;            p += (size_t)NTOT*KNN*4;
    float*  ABTf   = (float*)p;          p += 65536*4;
    float*  W2Tf   = (float*)p;          p += 32768*4;
    int*    perm   = (int*)p;            p += (size_t)NTOT*4;
    int*    cnt    = (int*)p;            p += 2*NCELL*4;
    int*    cellstart = (int*)p;         p += (2*NCELL+8)*4;
    int*    cursor = (int*)p;            p += 2*NCELL*4;
    // total ~53 MB

    hipMemsetAsync(cnt, 0, 2*NCELL*sizeof(int), stream);
    prep_kernel   <<<384, 256, 0, stream>>>(W1, W2, ABTf, W2Tf);
    count_kernel  <<<NTOT/256, 256, 0, stream>>>(coords, cnt);
    scan_kernel   <<<1, 1024, 0, stream>>>(cnt, cellstart, cursor);
    scatter_kernel<<<NTOT/256, 256, 0, stream>>>(coords, cursor, sorted, perm);
    knn_region_kernel<<<2*256*2, 256, 0, stream>>>(sorted, cellstart, knn_d2, knn_idx);
    gemm_split_kernel<CDIM, false, true, false>
        <<<dim3(NTOT/128, 2), 256, 0, stream>>>(
            feats, ABTf, nullptr, perm, nullptr, PQ, NTOT, CDIM);
    combine_kernel<<<NTOT, 128, 0, stream>>>(PQ, knn_d2, knn_idx, b1, hbar);
    gemm_split_kernel<IDIM, true, false, true>
        <<<dim3(NTOT/128, 2), 256, 0, stream>>>(
            hbar, W2Tf, b2, nullptr, perm, out, NTOT, CDIM);
}